// Round 6
// baseline (313.818 us; speedup 1.0000x reference)
//
#include <hip/hip_runtime.h>
#include <hip/hip_bf16.h>
#include <math.h>

// Problem constants
#define D_MODEL 512
#define D_STATE 16
#define DT_RANK 32
#define D_INNER 512
#define BB 4
#define LL 2048
#define MROWS (BB * LL)   // 8192
#define LN_EPS 1e-5f
#define CHUNK 32
#define NCH (LL / CHUNK)  // 64
#define LOG2E 1.44269504f

typedef __bf16 bf16x8 __attribute__((ext_vector_type(8)));
typedef float f32x4 __attribute__((ext_vector_type(4)));

// ---- bf16 split helpers (RNE) ----
__device__ __forceinline__ ushort f2bf(float x) {
  uint u = __float_as_uint(x);
  u = (u + 0x7fffu + ((u >> 16) & 1u)) >> 16;
  return (ushort)u;
}
__device__ __forceinline__ float bf2f(ushort h) {
  return __uint_as_float(((uint)h) << 16);
}
__device__ __forceinline__ void split2(float x, ushort& hi, ushort& lo) {
  hi = f2bf(x);
  lo = f2bf(x - bf2f(hi));
}

__device__ __forceinline__ void gload_lds16(const void* g, void* l) {
  __builtin_amdgcn_global_load_lds(
      (const __attribute__((address_space(1))) uint32_t*)g,
      (__attribute__((address_space(3))) uint32_t*)l, 16, 0, 0);
}

// ================= split-bf16 MFMA GEMM: C(M,N) = A(M,K) @ B(N,K)^T ==========
// 128x128 tile, BK=32, single-buffer LDS, 2 barriers/step (proven structure),
// + XCD-chunked block swizzle + LDS XOR-swizzle (both verified in isolation).
// A,B bf16 hi/lo pairs, row-major [rows][K]. C fp32.
// EPI 0: C=acc.  EPI 1: relu(acc + e0[(row>>11)*512+col]).
// EPI 3: col<512 -> C[row*512+col]=softplus(acc+e0[col]); 512<=col<544 ->
//        aux[row*32+col-512]=acc; col>=544 -> skip.
template <int EPI>
__global__ __launch_bounds__(256) void gemm_mfma(const ushort* __restrict__ Ahi,
                                                 const ushort* __restrict__ Alo,
                                                 const ushort* __restrict__ Bhi,
                                                 const ushort* __restrict__ Blo,
                                                 float* __restrict__ C, int ldc, int K,
                                                 int nx, const float* __restrict__ e0,
                                                 float* __restrict__ aux) {
  __shared__ ushort sAhi[128][32];
  __shared__ ushort sAlo[128][32];
  __shared__ ushort sBhi[128][32];
  __shared__ ushort sBlo[128][32];

  const int tid = threadIdx.x;
  const int lane = tid & 63;
  const int wid = tid >> 6;  // 0..3

  // XCD-chunked bijective swizzle (all grids are multiples of 8)
  const int nwg = gridDim.x;
  const int q = nwg >> 3;
  const int t = (blockIdx.x & 7) * q + (blockIdx.x >> 3);
  const int bx = t % nx;
  const int by = t / nx;
  const int m0 = by * 128;
  const int n0 = bx * 128;

  // staging: wave wid covers rows wid*32 + srow (+16); XOR-swizzled k slot
  const int srow = lane >> 2;                              // 0..15
  const int koff = (((lane & 3) ^ ((lane >> 3) & 3)) << 3);
  const ushort* gAh = Ahi + (size_t)(m0 + wid * 32 + srow) * K + koff;
  const ushort* gAl = Alo + (size_t)(m0 + wid * 32 + srow) * K + koff;
  const ushort* gBh = Bhi + (size_t)(n0 + wid * 32 + srow) * K + koff;
  const ushort* gBl = Blo + (size_t)(n0 + wid * 32 + srow) * K + koff;
  const int wrow = wid * 32;  // wave-uniform LDS row base
  const size_t rstep = (size_t)16 * K;

  // compute addressing: 2x2 waves, each 64x64
  const int wr = wid >> 1, wc = wid & 1;
  const int fr = lane & 15;
  const int rcs = (((lane >> 4) ^ ((fr >> 1) & 3)) << 3);  // swizzled read slot
  const int arow = wr * 64 + fr;
  const int brow = wc * 64 + fr;

  f32x4 acc[4][4] = {};

  for (int k0 = 0; k0 < K; k0 += 32) {
    __syncthreads();  // readers of previous tile done
    gload_lds16(gAh + k0,         &sAhi[wrow][0]);
    gload_lds16(gAh + k0 + rstep, &sAhi[wrow + 16][0]);
    gload_lds16(gAl + k0,         &sAlo[wrow][0]);
    gload_lds16(gAl + k0 + rstep, &sAlo[wrow + 16][0]);
    gload_lds16(gBh + k0,         &sBhi[wrow][0]);
    gload_lds16(gBh + k0 + rstep, &sBhi[wrow + 16][0]);
    gload_lds16(gBl + k0,         &sBlo[wrow][0]);
    gload_lds16(gBl + k0 + rstep, &sBlo[wrow + 16][0]);
    __syncthreads();  // staged data visible

    bf16x8 Ah[4], Al[4], Bh[4], Bl[4];
#pragma unroll
    for (int i = 0; i < 4; ++i) {
      Ah[i] = *(const bf16x8*)&sAhi[arow + i * 16][rcs];
      Al[i] = *(const bf16x8*)&sAlo[arow + i * 16][rcs];
      Bh[i] = *(const bf16x8*)&sBhi[brow + i * 16][rcs];
      Bl[i] = *(const bf16x8*)&sBlo[brow + i * 16][rcs];
    }
#pragma unroll
    for (int mi = 0; mi < 4; ++mi)
#pragma unroll
      for (int ni = 0; ni < 4; ++ni) {
        acc[mi][ni] = __builtin_amdgcn_mfma_f32_16x16x32_bf16(Ah[mi], Bh[ni],
                                                              acc[mi][ni], 0, 0, 0);
        acc[mi][ni] = __builtin_amdgcn_mfma_f32_16x16x32_bf16(Ah[mi], Bl[ni],
                                                              acc[mi][ni], 0, 0, 0);
        acc[mi][ni] = __builtin_amdgcn_mfma_f32_16x16x32_bf16(Al[mi], Bh[ni],
                                                              acc[mi][ni], 0, 0, 0);
      }
  }

  // epilogue: C/D layout col = lane&15, row = (lane>>4)*4 + r
  const int rbase = (lane >> 4) * 4;
#pragma unroll
  for (int mi = 0; mi < 4; ++mi) {
    const int row0 = m0 + wr * 64 + mi * 16 + rbase;
#pragma unroll
    for (int ni = 0; ni < 4; ++ni) {
      const int col = n0 + wc * 64 + ni * 16 + fr;
#pragma unroll
      for (int r = 0; r < 4; ++r) {
        float v = acc[mi][ni][r];
        const int row = row0 + r;
        if (EPI == 0) {
          C[(size_t)row * ldc + col] = v;
        } else if (EPI == 1) {
          v += e0[(row >> 11) * D_MODEL + col];
          C[(size_t)row * ldc + col] = fmaxf(v, 0.f);
        } else {  // EPI == 3
          if (col < 512) {
            float x = v + e0[col];
            C[(size_t)row * 512 + col] = (x > 20.f) ? x : log1pf(expf(x));
          } else if (col < 544) {
            aux[(size_t)row * 32 + (col - 512)] = v;
          }
        }
      }
    }
  }
}

// ---------------- splitters ---------------------------------------------------
__global__ __launch_bounds__(256) void split_x(const float* __restrict__ x,
                                               ushort* __restrict__ hi,
                                               ushort* __restrict__ lo) {
  const int i = (blockIdx.x * 256 + threadIdx.x) * 4;
  float4 v = *(const float4*)(x + i);
  ushort h0, l0, h1, l1, h2, l2, h3, l3;
  split2(v.x, h0, l0); split2(v.y, h1, l1); split2(v.z, h2, l2); split2(v.w, h3, l3);
  ushort4 hv = {h0, h1, h2, h3}, lv = {l0, l1, l2, l3};
  *(ushort4*)(hi + i) = hv;
  *(ushort4*)(lo + i) = lv;
}

// weight splitter rows 0..2047: [gW1a | in_proj_W | out_proj_W]
__global__ __launch_bounds__(128) void split_w(const float* __restrict__ gW1,
                                               const float* __restrict__ ipW,
                                               const float* __restrict__ opW,
                                               ushort* __restrict__ Whi,
                                               ushort* __restrict__ Wlo) {
  const int r = blockIdx.x;
  const int t = threadIdx.x;
  const float* src;
  if (r < 512) src = gW1 + (size_t)r * 1024;
  else if (r < 1536) src = ipW + (size_t)(r - 512) * 512;
  else src = opW + (size_t)(r - 1536) * 512;
  const int i = t * 4;
  float4 v = *(const float4*)(src + i);
  ushort h0, l0, h1, l1, h2, l2, h3, l3;
  split2(v.x, h0, l0); split2(v.y, h1, l1); split2(v.z, h2, l2); split2(v.w, h3, l3);
  ushort4 hv = {h0, h1, h2, h3}, lv = {l0, l1, l2, l3};
  *(ushort4*)(Whi + (size_t)r * 512 + i) = hv;
  *(ushort4*)(Wlo + (size_t)r * 512 + i) = lv;
}

// fused x-projection weight rows 2048..2687 (N padded to 640):
//  j<512:  W_comb[j] = dt_proj_W[j,:] @ x_proj_W[:32,:]   (512x512)
//  512<=j<544: x_proj_W rows 32..63 (B,C rows)
//  544<=j<640: zeros (N padding)
__global__ __launch_bounds__(128) void build_xw(const float* __restrict__ xW,
                                                const float* __restrict__ dtW,
                                                ushort* __restrict__ Whi,
                                                ushort* __restrict__ Wlo) {
  const int j = blockIdx.x;
  const int t = threadIdx.x;
  float v[4] = {0.f, 0.f, 0.f, 0.f};
  if (j < 512) {
    __shared__ float sdt[32];
    if (t < 32) sdt[t] = dtW[j * 32 + t];
    __syncthreads();
    const int k = t * 4;
#pragma unroll 8
    for (int r = 0; r < 32; ++r) {
      const float w = sdt[r];
      const float4 xv = *(const float4*)(xW + r * 512 + k);
      v[0] = fmaf(w, xv.x, v[0]);
      v[1] = fmaf(w, xv.y, v[1]);
      v[2] = fmaf(w, xv.z, v[2]);
      v[3] = fmaf(w, xv.w, v[3]);
    }
  } else if (j < 544) {
    const float4 xv = *(const float4*)(xW + (size_t)(32 + j - 512) * 512 + t * 4);
    v[0] = xv.x; v[1] = xv.y; v[2] = xv.z; v[3] = xv.w;
  }
  ushort h[4], l[4];
#pragma unroll
  for (int c = 0; c < 4; ++c) split2(v[c], h[c], l[c]);
  const size_t off = (size_t)(2048 + j) * 512 + t * 4;
  ushort4 hv = {h[0], h[1], h[2], h[3]}, lv = {l[0], l[1], l[2], l[3]};
  *(ushort4*)(Whi + off) = hv;
  *(ushort4*)(Wlo + off) = lv;
}

// ---------------- per-batch constant -----------------------------------------
__global__ __launch_bounds__(512) void c1_kernel(const float* __restrict__ xstats,
                                                 const float* __restrict__ gW1,
                                                 const float* __restrict__ gb1,
                                                 float* __restrict__ c1) {
  const int b = blockIdx.x;
  const int j = threadIdx.x;
  float acc = gb1[j];
  const float* xs = xstats + b * D_MODEL;
  const float* w = gW1 + (size_t)j * (2 * D_MODEL) + D_MODEL;
  for (int k = 0; k < D_MODEL; k += 4) {
    acc = fmaf(xs[k], w[k], acc);
    acc = fmaf(xs[k + 1], w[k + 1], acc);
    acc = fmaf(xs[k + 2], w[k + 2], acc);
    acc = fmaf(xs[k + 3], w[k + 3], acc);
  }
  c1[b * D_MODEL + j] = acc;
}

// ---------------- block reduce ------------------------------------------------
__device__ __forceinline__ float block_sum(float v, float* sm) {
#pragma unroll
  for (int m = 32; m; m >>= 1) v += __shfl_xor(v, m);
  const int lane = threadIdx.x & 63, w = threadIdx.x >> 6;
  __syncthreads();
  if (!lane) sm[w] = v;
  __syncthreads();
  return sm[0] + sm[1] + sm[2] + sm[3];
}

// ---------------- gate + layernorm (writes bf16 hi/lo) -------------------------
__global__ __launch_bounds__(256) void gate_ln_kernel(const float* __restrict__ H,
                                                      const float* __restrict__ xsig,
                                                      const float* __restrict__ xstats,
                                                      const float* __restrict__ gW2,
                                                      const float* __restrict__ gb2,
                                                      const float* __restrict__ ln_g,
                                                      const float* __restrict__ ln_b,
                                                      ushort* __restrict__ XNhi,
                                                      ushort* __restrict__ XNlo) {
  __shared__ float red[4];
  const int row = blockIdx.x;
  const int b = row >> 11;
  const int tid = threadIdx.x;
  const size_t rb = (size_t)row * D_MODEL;

  float dotv = 0.f;
  for (int j = tid; j < D_MODEL; j += 256) dotv = fmaf(H[rb + j], gW2[j], dotv);
  const float s = block_sum(dotv, red);
  const float gate = 1.f / (1.f + expf(-(s + gb2[0])));

  float xr[2];
#pragma unroll
  for (int ii = 0; ii < 2; ++ii) {
    const int j = tid + ii * 256;
    xr[ii] = xsig[rb + j] + gate * xstats[b * D_MODEL + j];
  }
  float sv = xr[0] + xr[1];
  const float mu = block_sum(sv, red) * (1.f / D_MODEL);
  float s2 = (xr[0] - mu) * (xr[0] - mu) + (xr[1] - mu) * (xr[1] - mu);
  const float var = block_sum(s2, red) * (1.f / D_MODEL);
  const float inv = rsqrtf(var + LN_EPS);
#pragma unroll
  for (int ii = 0; ii < 2; ++ii) {
    const int j = tid + ii * 256;
    const float v = (xr[ii] - mu) * inv * ln_g[j] + ln_b[j];
    ushort h, l;
    split2(v, h, l);
    XNhi[rb + j] = h;
    XNlo[rb + j] = l;
  }
}

// ---------------- causal conv(2) + SiLU (emits f32 + bf16 hi/lo) ---------------
__global__ __launch_bounds__(256) void conv_silu_kernel(const float* __restrict__ XZ,
                                                        const float* __restrict__ conv_w,
                                                        const float* __restrict__ conv_b,
                                                        float* __restrict__ U,
                                                        ushort* __restrict__ Uhi,
                                                        ushort* __restrict__ Ulo) {
  const int row = blockIdx.x;
  const bool first = (row & (LL - 1)) == 0;
  const int tid = threadIdx.x;
#pragma unroll
  for (int ii = 0; ii < 2; ++ii) {
    const int j = tid + ii * 256;
    const float up = first ? 0.f : XZ[(size_t)(row - 1) * (2 * D_INNER) + j];
    const float uc = XZ[(size_t)row * (2 * D_INNER) + j];
    float v = conv_b[j] + conv_w[j * 2 + 0] * up + conv_w[j * 2 + 1] * uc;
    v = v / (1.f + expf(-v));
    U[(size_t)row * D_INNER + j] = v;
    ushort h, l;
    split2(v, h, l);
    Uhi[(size_t)row * D_INNER + j] = h;
    Ulo[(size_t)row * D_INNER + j] = l;
  }
}

// ---------------- chunked selective scan (lane = channel, states in regs) ------
__global__ __launch_bounds__(256) void scan_part1(const float* __restrict__ DELTA,
                                                  const float* __restrict__ U,
                                                  const float* __restrict__ BC,
                                                  const float* __restrict__ A_log,
                                                  float* __restrict__ SLOC,
                                                  float* __restrict__ DSUM) {
  __shared__ __align__(16) float sBC[CHUNK][32];
  const int tid = threadIdx.x;
  const int bid = blockIdx.x;
  const int d = ((bid & 1) << 8) + tid;
  const int c = (bid >> 1) & (NCH - 1);
  const int b = bid >> 7;
  const size_t base = (size_t)b * LL + (size_t)c * CHUNK;

  {
    const int row = tid >> 3, col = (tid & 7) << 2;
    *(float4*)&sBC[row][col] = *(const float4*)(BC + (base + row) * 32 + col);
  }
  float A2[16];
#pragma unroll
  for (int n = 0; n < 16; ++n) A2[n] = -expf(A_log[d * 16 + n]) * LOG2E;
  __syncthreads();

  float S[16];
#pragma unroll
  for (int n = 0; n < 16; ++n) S[n] = 0.f;
  float dsum = 0.f;

#pragma unroll 2
  for (int t = 0; t < CHUNK; ++t) {
    const size_t r = base + t;
    const float delta = DELTA[r * D_INNER + d];
    const float u = U[r * D_INNER + d];
    dsum += delta;
    const float du = delta * u;
    float Bv[16];
#pragma unroll
    for (int i = 0; i < 4; ++i)
      *(float4*)&Bv[i * 4] = *(const float4*)&sBC[t][i * 4];
#pragma unroll
    for (int n = 0; n < 16; ++n) {
      const float dA = __builtin_amdgcn_exp2f(delta * A2[n]);
      S[n] = fmaf(dA, S[n], du * Bv[n]);
    }
  }
  const size_t ci = ((size_t)b * NCH + c) * D_INNER + d;
#pragma unroll
  for (int i = 0; i < 4; ++i)
    *(float4*)(SLOC + ci * 16 + i * 4) = *(const float4*)&S[i * 4];
  DSUM[ci] = dsum;
}

__global__ __launch_bounds__(256) void scan_combine(const float* __restrict__ SLOC,
                                                    const float* __restrict__ DSUM,
                                                    const float* __restrict__ A_log,
                                                    float* __restrict__ HINIT) {
  const int idx = blockIdx.x * 256 + threadIdx.x;  // 0..32767
  const int b = idx >> 13;
  const int d = (idx >> 4) & (D_INNER - 1);
  const int n = idx & 15;
  const float A2 = -expf(A_log[d * D_STATE + n]) * LOG2E;
  float h = 0.f;
#pragma unroll 4
  for (int c = 0; c < NCH; ++c) {
    const size_t ci = ((size_t)b * NCH + c) * D_INNER + d;
    HINIT[ci * 16 + n] = h;
    const float a = __builtin_amdgcn_exp2f(A2 * DSUM[ci]);
    h = fmaf(a, h, SLOC[ci * 16 + n]);
  }
}

__global__ __launch_bounds__(256) void scan_part3(const float* __restrict__ DELTA,
                                                  const float* __restrict__ U,
                                                  const float* __restrict__ BC,
                                                  const float* __restrict__ XZ,
                                                  const float* __restrict__ A_log,
                                                  const float* __restrict__ Dp,
                                                  const float* __restrict__ HINIT,
                                                  ushort* __restrict__ Yhi,
                                                  ushort* __restrict__ Ylo) {
  __shared__ __align__(16) float sBC[CHUNK][32];
  const int tid = threadIdx.x;
  const int bid = blockIdx.x;
  const int d = ((bid & 1) << 8) + tid;
  const int c = (bid >> 1) & (NCH - 1);
  const int b = bid >> 7;
  const size_t base = (size_t)b * LL + (size_t)c * CHUNK;

  {
    const int row = tid >> 3, col = (tid & 7) << 2;
    *(float4*)&sBC[row][col] = *(const float4*)(BC + (base + row) * 32 + col);
  }
  float A2[16];
#pragma unroll
  for (int n = 0; n < 16; ++n) A2[n] = -expf(A_log[d * 16 + n]) * LOG2E;
  const float Dpd = Dp[d];

  const size_t ci = ((size_t)b * NCH + c) * D_INNER + d;
  float h[16];
#pragma unroll
  for (int i = 0; i < 4; ++i)
    *(float4*)&h[i * 4] = *(const float4*)(HINIT + ci * 16 + i * 4);
  __syncthreads();

#pragma unroll 2
  for (int t = 0; t < CHUNK; ++t) {
    const size_t r = base + t;
    const float delta = DELTA[r * D_INNER + d];
    const float u = U[r * D_INNER + d];
    const float z = XZ[r * (2 * D_INNER) + D_INNER + d];
    const float du = delta * u;
    float BCv[32];
#pragma unroll
    for (int i = 0; i < 8; ++i)
      *(float4*)&BCv[i * 4] = *(const float4*)&sBC[t][i * 4];
    float y = 0.f;
#pragma unroll
    for (int n = 0; n < 16; ++n) {
      const float dA = __builtin_amdgcn_exp2f(delta * A2[n]);
      h[n] = fmaf(dA, h[n], du * BCv[n]);
      y = fmaf(h[n], BCv[16 + n], y);
    }
    const float sz = z / (1.f + __builtin_amdgcn_exp2f(-z * LOG2E));
    const float o = (y + Dpd * u) * sz;
    ushort hh, ll;
    split2(o, hh, ll);
    Yhi[r * D_INNER + d] = hh;
    Ylo[r * D_INNER + d] = ll;
  }
}

// =============================================================================
extern "C" void kernel_launch(void* const* d_in, const int* in_sizes, int n_in,
                              void* d_out, int out_size, void* d_ws, size_t ws_size,
                              hipStream_t stream) {
  const float* x_signal = (const float*)d_in[0];
  const float* x_stats  = (const float*)d_in[1];
  const float* gW1      = (const float*)d_in[2];
  const float* gb1      = (const float*)d_in[3];
  const float* gW2      = (const float*)d_in[4];
  const float* gb2      = (const float*)d_in[5];
  const float* ln_g     = (const float*)d_in[6];
  const float* ln_b     = (const float*)d_in[7];
  const float* in_proj_W = (const float*)d_in[8];
  const float* conv_w   = (const float*)d_in[9];
  const float* conv_b   = (const float*)d_in[10];
  const float* x_proj_W = (const float*)d_in[11];
  const float* dt_proj_W = (const float*)d_in[12];
  const float* dt_proj_b = (const float*)d_in[13];
  const float* A_log    = (const float*)d_in[14];
  const float* Dp       = (const float*)d_in[15];
  const float* out_proj_W = (const float*)d_in[16];
  float* out = (float*)d_out;

  float* ws = (float*)d_ws;
  const size_t NE = (size_t)MROWS * D_MODEL;  // 4,194,304
  float* H    = ws;                     // gate GEMM out; reused as Yhi/Ylo
  float* XNf  = H + NE;                 // XN hi/lo bf16; later DELTA f32
  float* XZ   = XNf + NE;               // 8192x1024 f32; first XShi/XSlo
  float* U    = XZ + 2 * NE;            // f32
  float* UHL  = U + NE;                 // Uhi/Ulo bf16
  float* BC   = UHL + NE;               // 8192x32 f32
  float* C1   = BC + (size_t)MROWS * 32;
  float* SLOC = C1 + BB * D_MODEL;
  float* DSUM = SLOC + (size_t)BB * NCH * D_INNER * D_STATE;
  float* HINIT = DSUM + (size_t)BB * NCH * D_INNER;
  float* WSP  = HINIT + (size_t)BB * NCH * D_INNER * D_STATE;

  ushort* XNhi = (ushort*)XNf;
  ushort* XNlo = XNhi + NE;
  ushort* XShi = (ushort*)XZ;
  ushort* XSlo = XShi + NE;
  ushort* Yhi  = (ushort*)H;
  ushort* Ylo  = Yhi + NE;
  ushort* Uhi  = (ushort*)UHL;
  ushort* Ulo  = Uhi + NE;
  ushort* Whi  = (ushort*)WSP;          // 2688 rows x 512
  ushort* Wlo  = Whi + (size_t)2688 * 512;
  float* DELTA = XNf;

  // 0) splits + fused x-projection weight
  split_x<<<dim3(NE / 1024), dim3(256), 0, stream>>>(x_signal, XShi, XSlo);
  split_w<<<dim3(2048), dim3(128), 0, stream>>>(gW1, in_proj_W, out_proj_W, Whi, Wlo);
  build_xw<<<dim3(640), dim3(128), 0, stream>>>(x_proj_W, dt_proj_W, Whi, Wlo);

  // 1) per-batch xs @ W1b.T + gb1
  c1_kernel<<<dim3(BB), dim3(512), 0, stream>>>(x_stats, gW1, gb1, C1);

  // 2) H = relu(x_signal @ W1a.T + c1)   (grid 4x64 = 256)
  gemm_mfma<1><<<dim3(4 * 64), dim3(256), 0, stream>>>(
      XShi, XSlo, Whi, Wlo, H, D_MODEL, D_MODEL, 4, C1, nullptr);

  // 3) gate + layernorm -> XNhi/XNlo
  gate_ln_kernel<<<dim3(MROWS), dim3(256), 0, stream>>>(H, x_signal, x_stats, gW2, gb2,
                                                        ln_g, ln_b, XNhi, XNlo);

  // 4) XZ = XN @ in_proj_W.T   (grid 8x64 = 512)
  gemm_mfma<0><<<dim3(8 * 64), dim3(256), 0, stream>>>(
      XNhi, XNlo, Whi + (size_t)512 * 512, Wlo + (size_t)512 * 512, XZ, 2 * D_INNER,
      D_MODEL, 8, nullptr, nullptr);

  // 5) conv + silu -> U (f32 + hi/lo)
  conv_silu_kernel<<<dim3(MROWS), dim3(256), 0, stream>>>(XZ, conv_w, conv_b, U, Uhi,
                                                          Ulo);

  // 6) fused x-projection: DELTA = softplus(U @ Wcomb.T + dtb), BC = U @ xWbc.T
  //    (grid 5x64 = 320, N padded to 640)
  gemm_mfma<3><<<dim3(5 * 64), dim3(256), 0, stream>>>(
      Uhi, Ulo, Whi + (size_t)2048 * 512, Wlo + (size_t)2048 * 512, DELTA, 512,
      D_MODEL, 5, dt_proj_b, BC);

  // 7) chunked selective scan -> Yhi/Ylo
  scan_part1<<<dim3(BB * NCH * 2), dim3(256), 0, stream>>>(DELTA, U, BC, A_log,
                                                           SLOC, DSUM);
  scan_combine<<<dim3(128), dim3(256), 0, stream>>>(SLOC, DSUM, A_log, HINIT);
  scan_part3<<<dim3(BB * NCH * 2), dim3(256), 0, stream>>>(DELTA, U, BC, XZ, A_log,
                                                           Dp, HINIT, Yhi, Ylo);

  // 8) out = Y @ out_proj_W.T   (grid 4x64 = 256)
  gemm_mfma<0><<<dim3(4 * 64), dim3(256), 0, stream>>>(
      Yhi, Ylo, Whi + (size_t)1536 * 512, Wlo + (size_t)1536 * 512, out, D_MODEL,
      D_INNER, 4, nullptr, nullptr);
}

// Round 7
// 237.205 us; speedup vs baseline: 1.3230x; 1.3230x over previous
//
#include <hip/hip_runtime.h>
#include <hip/hip_bf16.h>
#include <math.h>

// Problem constants
#define D_MODEL 512
#define D_STATE 16
#define DT_RANK 32
#define D_INNER 512
#define BB 4
#define LL 2048
#define MROWS (BB * LL)   // 8192
#define LN_EPS 1e-5f
#define CHUNK 32
#define NCH (LL / CHUNK)  // 64
#define LOG2E 1.44269504f

typedef __bf16 bf16x8 __attribute__((ext_vector_type(8)));
typedef float f32x4 __attribute__((ext_vector_type(4)));

// ---- bf16 split helpers (RNE) ----
__device__ __forceinline__ ushort f2bf(float x) {
  uint u = __float_as_uint(x);
  u = (u + 0x7fffu + ((u >> 16) & 1u)) >> 16;
  return (ushort)u;
}
__device__ __forceinline__ float bf2f(ushort h) {
  return __uint_as_float(((uint)h) << 16);
}
__device__ __forceinline__ void split2(float x, ushort& hi, ushort& lo) {
  hi = f2bf(x);
  lo = f2bf(x - bf2f(hi));
}

__device__ __forceinline__ void gload_lds16(const void* g, void* l) {
  __builtin_amdgcn_global_load_lds(
      (const __attribute__((address_space(1))) uint32_t*)g,
      (__attribute__((address_space(3))) uint32_t*)l, 16, 0, 0);
}

// ================= split-bf16 MFMA GEMM (round-5 structure, best measured) ====
// Tile 128x64, BK=32, double-buffered LDS + issue-early prefetch, LDS XOR
// swizzle, XCD-chunked block swizzle. A,B bf16 hi/lo pairs row-major [rows][K].
// EPI 0: C=acc.  EPI 1: relu(acc + e0[(row>>11)*512+col]).
template <int EPI>
__global__ __launch_bounds__(256) void gemm_mfma(const ushort* __restrict__ Ahi,
                                                 const ushort* __restrict__ Alo,
                                                 const ushort* __restrict__ Bhi,
                                                 const ushort* __restrict__ Blo,
                                                 float* __restrict__ C, int ldc, int K,
                                                 int nx, const float* __restrict__ e0) {
  __shared__ ushort sA[2][2][128][32];  // [buf][hi/lo][row][col]  32 KiB
  __shared__ ushort sB[2][2][64][32];   // 16 KiB

  const int tid = threadIdx.x;
  const int lane = tid & 63;
  const int wid = tid >> 6;  // 0..3

  // XCD-chunked bijective swizzle (nwg % 8 == 0 for all our grids)
  const int nwg = gridDim.x;
  const int q = nwg >> 3;
  const int t = (blockIdx.x & 7) * q + (blockIdx.x >> 3);
  const int bx = t % nx;
  const int by = t / nx;
  const int m0 = by * 128;
  const int n0 = bx * 64;

  // ---- staging addressing (pre-swizzled global source, linear LDS dest) ----
  const int srow = tid >> 2;                                  // 0..63
  const int koff = (((tid & 3) ^ ((tid >> 3) & 3)) << 3);     // swizzled k slot
  const ushort* Ah_p = Ahi + (size_t)(m0 + srow) * K + koff;
  const ushort* Al_p = Alo + (size_t)(m0 + srow) * K + koff;
  const ushort* Bh_p = Bhi + (size_t)(n0 + srow) * K + koff;
  const ushort* Bl_p = Blo + (size_t)(n0 + srow) * K + koff;
  const size_t rstep = (size_t)64 * K;
  const int wb = wid * 16;  // wave-uniform LDS row base

  // ---- compute addressing ----
  const int wr = wid >> 1, wc = wid & 1;     // wave 2x2 -> 64x32 sub-tile
  const int fr = lane & 15;
  const int rcs = (((lane >> 4) ^ ((fr >> 1) & 3)) << 3);  // swizzled read slot

  f32x4 acc[4][2] = {};

  auto STAGE = [&](int bq, int kk) {
    gload_lds16(Ah_p + kk,         &sA[bq][0][wb][0]);
    gload_lds16(Ah_p + kk + rstep, &sA[bq][0][64 + wb][0]);
    gload_lds16(Al_p + kk,         &sA[bq][1][wb][0]);
    gload_lds16(Al_p + kk + rstep, &sA[bq][1][64 + wb][0]);
    gload_lds16(Bh_p + kk,         &sB[bq][0][wb][0]);
    gload_lds16(Bl_p + kk,         &sB[bq][1][wb][0]);
  };

  int cur = 0;
  STAGE(0, 0);
  __syncthreads();

  for (int k0 = 0; k0 < K; k0 += 32) {
    if (k0 + 32 < K) STAGE(cur ^ 1, k0 + 32);  // prefetch in flight under MFMA
    bf16x8 ah[4], al[4], bh[2], bl[2];
#pragma unroll
    for (int m = 0; m < 4; ++m) {
      const int ar = wr * 64 + m * 16 + fr;
      ah[m] = *(const bf16x8*)&sA[cur][0][ar][rcs];
      al[m] = *(const bf16x8*)&sA[cur][1][ar][rcs];
    }
#pragma unroll
    for (int n = 0; n < 2; ++n) {
      const int br = wc * 32 + n * 16 + fr;
      bh[n] = *(const bf16x8*)&sB[cur][0][br][rcs];
      bl[n] = *(const bf16x8*)&sB[cur][1][br][rcs];
    }
#pragma unroll
    for (int m = 0; m < 4; ++m)
#pragma unroll
      for (int n = 0; n < 2; ++n) {
        acc[m][n] = __builtin_amdgcn_mfma_f32_16x16x32_bf16(ah[m], bh[n],
                                                            acc[m][n], 0, 0, 0);
        acc[m][n] = __builtin_amdgcn_mfma_f32_16x16x32_bf16(ah[m], bl[n],
                                                            acc[m][n], 0, 0, 0);
        acc[m][n] = __builtin_amdgcn_mfma_f32_16x16x32_bf16(al[m], bh[n],
                                                            acc[m][n], 0, 0, 0);
      }
    __syncthreads();
    cur ^= 1;
  }

  // epilogue: C/D layout col = lane&15, row = (lane>>4)*4 + r
  const int rbase = (lane >> 4) * 4;
#pragma unroll
  for (int m = 0; m < 4; ++m) {
    const int row0 = m0 + wr * 64 + m * 16 + rbase;
#pragma unroll
    for (int n = 0; n < 2; ++n) {
      const int col = n0 + wc * 32 + n * 16 + fr;
#pragma unroll
      for (int r = 0; r < 4; ++r) {
        float v = acc[m][n][r];
        const int row = row0 + r;
        if (EPI == 1) {
          v += e0[(row >> 11) * D_MODEL + col];
          v = fmaxf(v, 0.f);
        }
        C[(size_t)row * ldc + col] = v;
      }
    }
  }
}

// ---------------- fp32 tiled GEMM (small shapes; r4-measured) -----------------
#define TBM 64
#define TBN 64
#define TBK 16

template <int EPI>
__global__ __launch_bounds__(256) void gemm_tn(const float* __restrict__ A, int lda,
                                               const float* __restrict__ B, int ldb,
                                               float* __restrict__ C, int ldc,
                                               int M, int N, int K,
                                               const float* __restrict__ e0) {
  __shared__ __align__(16) float As[TBK][TBM];
  __shared__ __align__(16) float Bs[TBK][TBN];
  const int tid = threadIdx.x;
  const int tx = tid & 15;
  const int ty = tid >> 4;
  const int m0 = blockIdx.y * TBM;
  const int n0 = blockIdx.x * TBN;
  const int lr = tid >> 2;
  const int lk = (tid & 3) << 2;

  float acc[4][4] = {};

  for (int k0 = 0; k0 < K; k0 += TBK) {
    float4 av = *(const float4*)(A + (size_t)(m0 + lr) * lda + k0 + lk);
    float4 bv = *(const float4*)(B + (size_t)(n0 + lr) * ldb + k0 + lk);
    __syncthreads();
    As[lk + 0][lr] = av.x; As[lk + 1][lr] = av.y;
    As[lk + 2][lr] = av.z; As[lk + 3][lr] = av.w;
    Bs[lk + 0][lr] = bv.x; Bs[lk + 1][lr] = bv.y;
    Bs[lk + 2][lr] = bv.z; Bs[lk + 3][lr] = bv.w;
    __syncthreads();
#pragma unroll
    for (int kk = 0; kk < TBK; ++kk) {
      float4 a4 = *(const float4*)(&As[kk][ty * 4]);
      float4 b4 = *(const float4*)(&Bs[kk][tx * 4]);
      float a[4] = {a4.x, a4.y, a4.z, a4.w};
      float b[4] = {b4.x, b4.y, b4.z, b4.w};
#pragma unroll
      for (int i = 0; i < 4; ++i)
#pragma unroll
        for (int j = 0; j < 4; ++j) acc[i][j] = fmaf(a[i], b[j], acc[i][j]);
    }
  }

#pragma unroll
  for (int i = 0; i < 4; ++i) {
    const int gr = m0 + ty * 4 + i;
#pragma unroll
    for (int j = 0; j < 4; ++j) {
      const int gc = n0 + tx * 4 + j;
      float v = acc[i][j];
      if (EPI == 2) {
        float x = v + e0[gc];
        v = (x > 20.f) ? x : log1pf(expf(x));
      }
      C[(size_t)gr * ldc + gc] = v;
    }
  }
}

// ---------------- splitters ---------------------------------------------------
__global__ __launch_bounds__(256) void split_x(const float* __restrict__ x,
                                               ushort* __restrict__ hi,
                                               ushort* __restrict__ lo) {
  const int i = (blockIdx.x * 256 + threadIdx.x) * 4;
  float4 v = *(const float4*)(x + i);
  ushort h0, l0, h1, l1, h2, l2, h3, l3;
  split2(v.x, h0, l0); split2(v.y, h1, l1); split2(v.z, h2, l2); split2(v.w, h3, l3);
  ushort4 hv = {h0, h1, h2, h3}, lv = {l0, l1, l2, l3};
  *(ushort4*)(hi + i) = hv;
  *(ushort4*)(lo + i) = lv;
}

// weight splitter rows 0..2047: [gW1a | in_proj_W | out_proj_W]
__global__ __launch_bounds__(128) void split_w(const float* __restrict__ gW1,
                                               const float* __restrict__ ipW,
                                               const float* __restrict__ opW,
                                               ushort* __restrict__ Whi,
                                               ushort* __restrict__ Wlo) {
  const int r = blockIdx.x;
  const int t = threadIdx.x;
  const float* src;
  if (r < 512) src = gW1 + (size_t)r * 1024;
  else if (r < 1536) src = ipW + (size_t)(r - 512) * 512;
  else src = opW + (size_t)(r - 1536) * 512;
  const int i = t * 4;
  float4 v = *(const float4*)(src + i);
  ushort h0, l0, h1, l1, h2, l2, h3, l3;
  split2(v.x, h0, l0); split2(v.y, h1, l1); split2(v.z, h2, l2); split2(v.w, h3, l3);
  ushort4 hv = {h0, h1, h2, h3}, lv = {l0, l1, l2, l3};
  *(ushort4*)(Whi + (size_t)r * 512 + i) = hv;
  *(ushort4*)(Wlo + (size_t)r * 512 + i) = lv;
}

// ---------------- per-batch constant -----------------------------------------
__global__ __launch_bounds__(512) void c1_kernel(const float* __restrict__ xstats,
                                                 const float* __restrict__ gW1,
                                                 const float* __restrict__ gb1,
                                                 float* __restrict__ c1) {
  const int b = blockIdx.x;
  const int j = threadIdx.x;
  float acc = gb1[j];
  const float* xs = xstats + b * D_MODEL;
  const float* w = gW1 + (size_t)j * (2 * D_MODEL) + D_MODEL;
  for (int k = 0; k < D_MODEL; k += 4) {
    acc = fmaf(xs[k], w[k], acc);
    acc = fmaf(xs[k + 1], w[k + 1], acc);
    acc = fmaf(xs[k + 2], w[k + 2], acc);
    acc = fmaf(xs[k + 3], w[k + 3], acc);
  }
  c1[b * D_MODEL + j] = acc;
}

// ---------------- block reduce ------------------------------------------------
__device__ __forceinline__ float block_sum(float v, float* sm) {
#pragma unroll
  for (int m = 32; m; m >>= 1) v += __shfl_xor(v, m);
  const int lane = threadIdx.x & 63, w = threadIdx.x >> 6;
  __syncthreads();
  if (!lane) sm[w] = v;
  __syncthreads();
  return sm[0] + sm[1] + sm[2] + sm[3];
}

// ---------------- gate + layernorm (writes bf16 hi/lo) -------------------------
__global__ __launch_bounds__(256) void gate_ln_kernel(const float* __restrict__ H,
                                                      const float* __restrict__ xsig,
                                                      const float* __restrict__ xstats,
                                                      const float* __restrict__ gW2,
                                                      const float* __restrict__ gb2,
                                                      const float* __restrict__ ln_g,
                                                      const float* __restrict__ ln_b,
                                                      ushort* __restrict__ XNhi,
                                                      ushort* __restrict__ XNlo) {
  __shared__ float red[4];
  const int row = blockIdx.x;
  const int b = row >> 11;
  const int tid = threadIdx.x;
  const size_t rb = (size_t)row * D_MODEL;

  float dotv = 0.f;
  for (int j = tid; j < D_MODEL; j += 256) dotv = fmaf(H[rb + j], gW2[j], dotv);
  const float s = block_sum(dotv, red);
  const float gate = 1.f / (1.f + expf(-(s + gb2[0])));

  float xr[2];
#pragma unroll
  for (int ii = 0; ii < 2; ++ii) {
    const int j = tid + ii * 256;
    xr[ii] = xsig[rb + j] + gate * xstats[b * D_MODEL + j];
  }
  float sv = xr[0] + xr[1];
  const float mu = block_sum(sv, red) * (1.f / D_MODEL);
  float s2 = (xr[0] - mu) * (xr[0] - mu) + (xr[1] - mu) * (xr[1] - mu);
  const float var = block_sum(s2, red) * (1.f / D_MODEL);
  const float inv = rsqrtf(var + LN_EPS);
#pragma unroll
  for (int ii = 0; ii < 2; ++ii) {
    const int j = tid + ii * 256;
    const float v = (xr[ii] - mu) * inv * ln_g[j] + ln_b[j];
    ushort h, l;
    split2(v, h, l);
    XNhi[rb + j] = h;
    XNlo[rb + j] = l;
  }
}

// ---------------- causal conv(2) + SiLU (f32 out only) -------------------------
__global__ __launch_bounds__(256) void conv_silu_kernel(const float* __restrict__ XZ,
                                                        const float* __restrict__ conv_w,
                                                        const float* __restrict__ conv_b,
                                                        float* __restrict__ U) {
  const int row = blockIdx.x;
  const bool first = (row & (LL - 1)) == 0;
  const int tid = threadIdx.x;
#pragma unroll
  for (int ii = 0; ii < 2; ++ii) {
    const int j = tid + ii * 256;
    const float up = first ? 0.f : XZ[(size_t)(row - 1) * (2 * D_INNER) + j];
    const float uc = XZ[(size_t)row * (2 * D_INNER) + j];
    float v = conv_b[j] + conv_w[j * 2 + 0] * up + conv_w[j * 2 + 1] * uc;
    v = v / (1.f + expf(-v));
    U[(size_t)row * D_INNER + j] = v;
  }
}

// ---------------- chunked selective scan (lane = channel, states in regs) ------
__global__ __launch_bounds__(256) void scan_part1(const float* __restrict__ DELTA,
                                                  const float* __restrict__ U,
                                                  const float* __restrict__ XDBC,
                                                  const float* __restrict__ A_log,
                                                  float* __restrict__ SLOC,
                                                  float* __restrict__ DSUM) {
  __shared__ __align__(16) float sBC[CHUNK][32];
  const int tid = threadIdx.x;
  const int bid = blockIdx.x;
  const int d = ((bid & 1) << 8) + tid;
  const int c = (bid >> 1) & (NCH - 1);
  const int b = bid >> 7;
  const size_t base = (size_t)b * LL + (size_t)c * CHUNK;

  {  // stage B|C columns (XDBC cols 32..63) for the chunk
    const int row = tid >> 3, col = (tid & 7) << 2;
    *(float4*)&sBC[row][col] = *(const float4*)(XDBC + (base + row) * 64 + 32 + col);
  }
  float A2[16];
#pragma unroll
  for (int n = 0; n < 16; ++n) A2[n] = -expf(A_log[d * 16 + n]) * LOG2E;
  __syncthreads();

  float S[16];
#pragma unroll
  for (int n = 0; n < 16; ++n) S[n] = 0.f;
  float dsum = 0.f;

#pragma unroll 2
  for (int t = 0; t < CHUNK; ++t) {
    const size_t r = base + t;
    const float delta = DELTA[r * D_INNER + d];
    const float u = U[r * D_INNER + d];
    dsum += delta;
    const float du = delta * u;
    float Bv[16];
#pragma unroll
    for (int i = 0; i < 4; ++i)
      *(float4*)&Bv[i * 4] = *(const float4*)&sBC[t][i * 4];
#pragma unroll
    for (int n = 0; n < 16; ++n) {
      const float dA = __builtin_amdgcn_exp2f(delta * A2[n]);
      S[n] = fmaf(dA, S[n], du * Bv[n]);
    }
  }
  const size_t ci = ((size_t)b * NCH + c) * D_INNER + d;
#pragma unroll
  for (int i = 0; i < 4; ++i)
    *(float4*)(SLOC + ci * 16 + i * 4) = *(const float4*)&S[i * 4];
  DSUM[ci] = dsum;
}

__global__ __launch_bounds__(256) void scan_combine(const float* __restrict__ SLOC,
                                                    const float* __restrict__ DSUM,
                                                    const float* __restrict__ A_log,
                                                    float* __restrict__ HINIT) {
  const int idx = blockIdx.x * 256 + threadIdx.x;  // 0..32767
  const int b = idx >> 13;
  const int d = (idx >> 4) & (D_INNER - 1);
  const int n = idx & 15;
  const float A2 = -expf(A_log[d * D_STATE + n]) * LOG2E;
  float h = 0.f;
#pragma unroll 4
  for (int c = 0; c < NCH; ++c) {
    const size_t ci = ((size_t)b * NCH + c) * D_INNER + d;
    HINIT[ci * 16 + n] = h;
    const float a = __builtin_amdgcn_exp2f(A2 * DSUM[ci]);
    h = fmaf(a, h, SLOC[ci * 16 + n]);
  }
}

__global__ __launch_bounds__(256) void scan_part3(const float* __restrict__ DELTA,
                                                  const float* __restrict__ U,
                                                  const float* __restrict__ XDBC,
                                                  const float* __restrict__ XZ,
                                                  const float* __restrict__ A_log,
                                                  const float* __restrict__ Dp,
                                                  const float* __restrict__ HINIT,
                                                  ushort* __restrict__ Yhi,
                                                  ushort* __restrict__ Ylo) {
  __shared__ __align__(16) float sBC[CHUNK][32];
  const int tid = threadIdx.x;
  const int bid = blockIdx.x;
  const int d = ((bid & 1) << 8) + tid;
  const int c = (bid >> 1) & (NCH - 1);
  const int b = bid >> 7;
  const size_t base = (size_t)b * LL + (size_t)c * CHUNK;

  {
    const int row = tid >> 3, col = (tid & 7) << 2;
    *(float4*)&sBC[row][col] = *(const float4*)(XDBC + (base + row) * 64 + 32 + col);
  }
  float A2[16];
#pragma unroll
  for (int n = 0; n < 16; ++n) A2[n] = -expf(A_log[d * 16 + n]) * LOG2E;
  const float Dpd = Dp[d];

  const size_t ci = ((size_t)b * NCH + c) * D_INNER + d;
  float h[16];
#pragma unroll
  for (int i = 0; i < 4; ++i)
    *(float4*)&h[i * 4] = *(const float4*)(HINIT + ci * 16 + i * 4);
  __syncthreads();

#pragma unroll 2
  for (int t = 0; t < CHUNK; ++t) {
    const size_t r = base + t;
    const float delta = DELTA[r * D_INNER + d];
    const float u = U[r * D_INNER + d];
    const float z = XZ[r * (2 * D_INNER) + D_INNER + d];
    const float du = delta * u;
    float BCv[32];
#pragma unroll
    for (int i = 0; i < 8; ++i)
      *(float4*)&BCv[i * 4] = *(const float4*)&sBC[t][i * 4];
    float y = 0.f;
#pragma unroll
    for (int n = 0; n < 16; ++n) {
      const float dA = __builtin_amdgcn_exp2f(delta * A2[n]);
      h[n] = fmaf(dA, h[n], du * BCv[n]);
      y = fmaf(h[n], BCv[16 + n], y);
    }
    const float sz = z / (1.f + __builtin_amdgcn_exp2f(-z * LOG2E));
    const float o = (y + Dpd * u) * sz;
    ushort hh, ll;
    split2(o, hh, ll);
    Yhi[r * D_INNER + d] = hh;
    Ylo[r * D_INNER + d] = ll;
  }
}

// =============================================================================
extern "C" void kernel_launch(void* const* d_in, const int* in_sizes, int n_in,
                              void* d_out, int out_size, void* d_ws, size_t ws_size,
                              hipStream_t stream) {
  const float* x_signal = (const float*)d_in[0];
  const float* x_stats  = (const float*)d_in[1];
  const float* gW1      = (const float*)d_in[2];
  const float* gb1      = (const float*)d_in[3];
  const float* gW2      = (const float*)d_in[4];
  const float* gb2      = (const float*)d_in[5];
  const float* ln_g     = (const float*)d_in[6];
  const float* ln_b     = (const float*)d_in[7];
  const float* in_proj_W = (const float*)d_in[8];
  const float* conv_w   = (const float*)d_in[9];
  const float* conv_b   = (const float*)d_in[10];
  const float* x_proj_W = (const float*)d_in[11];
  const float* dt_proj_W = (const float*)d_in[12];
  const float* dt_proj_b = (const float*)d_in[13];
  const float* A_log    = (const float*)d_in[14];
  const float* Dp       = (const float*)d_in[15];
  const float* out_proj_W = (const float*)d_in[16];
  float* out = (float*)d_out;

  float* ws = (float*)d_ws;
  const size_t NE = (size_t)MROWS * D_MODEL;  // 4,194,304
  float* H    = ws;                     // gate GEMM out; reused as Yhi/Ylo
  float* XNf  = H + NE;                 // XN hi/lo bf16; later DELTA f32
  float* XZ   = XNf + NE;               // 8192x1024 f32; first XShi/XSlo
  float* U    = XZ + 2 * NE;            // f32
  float* XDBC = U + NE;                 // 8192x64 f32
  float* C1   = XDBC + (size_t)MROWS * 64;
  float* SLOC = C1 + BB * D_MODEL;
  float* DSUM = SLOC + (size_t)BB * NCH * D_INNER * D_STATE;
  float* HINIT = DSUM + (size_t)BB * NCH * D_INNER;
  float* WSP  = HINIT + (size_t)BB * NCH * D_INNER * D_STATE;

  ushort* XNhi = (ushort*)XNf;
  ushort* XNlo = XNhi + NE;
  ushort* XShi = (ushort*)XZ;
  ushort* XSlo = XShi + NE;
  ushort* Yhi  = (ushort*)H;
  ushort* Ylo  = Yhi + NE;
  ushort* Whi  = (ushort*)WSP;          // 2048 rows x 512
  ushort* Wlo  = Whi + (size_t)2048 * 512;
  float* DELTA = XNf;

  // 0) splits
  split_x<<<dim3(NE / 1024), dim3(256), 0, stream>>>(x_signal, XShi, XSlo);
  split_w<<<dim3(2048), dim3(128), 0, stream>>>(gW1, in_proj_W, out_proj_W, Whi, Wlo);

  // 1) per-batch xs @ W1b.T + gb1
  c1_kernel<<<dim3(BB), dim3(512), 0, stream>>>(x_stats, gW1, gb1, C1);

  // 2) H = relu(x_signal @ W1a.T + c1)   (grid 8x64 = 512)
  gemm_mfma<1><<<dim3(8 * 64), dim3(256), 0, stream>>>(
      XShi, XSlo, Whi, Wlo, H, D_MODEL, D_MODEL, 8, C1);

  // 3) gate + layernorm -> XNhi/XNlo
  gate_ln_kernel<<<dim3(MROWS), dim3(256), 0, stream>>>(H, x_signal, x_stats, gW2, gb2,
                                                        ln_g, ln_b, XNhi, XNlo);

  // 4) XZ = XN @ in_proj_W.T   (grid 16x64 = 1024)
  gemm_mfma<0><<<dim3(16 * 64), dim3(256), 0, stream>>>(
      XNhi, XNlo, Whi + (size_t)512 * 512, Wlo + (size_t)512 * 512, XZ, 2 * D_INNER,
      D_MODEL, 16, nullptr);

  // 5) conv + silu -> U (f32)
  conv_silu_kernel<<<dim3(MROWS), dim3(256), 0, stream>>>(XZ, conv_w, conv_b, U);

  // 6) XDBC = U @ x_proj_W.T  (fp32 vector GEMM, N=64; r4-measured 25us)
  gemm_tn<0><<<dim3(64 / TBN, MROWS / TBM), dim3(256), 0, stream>>>(
      U, D_INNER, x_proj_W, D_INNER, XDBC, 64, MROWS, 64, D_INNER, nullptr);

  // 7) DELTA = softplus(dt @ dt_proj_W.T + dt_proj_b)  (K=32; r4-measured 18us)
  gemm_tn<2><<<dim3(D_INNER / TBN, MROWS / TBM), dim3(256), 0, stream>>>(
      XDBC, 64, dt_proj_W, DT_RANK, DELTA, D_INNER, MROWS, D_INNER, DT_RANK, dt_proj_b);

  // 8) chunked selective scan -> Yhi/Ylo
  scan_part1<<<dim3(BB * NCH * 2), dim3(256), 0, stream>>>(DELTA, U, XDBC, A_log,
                                                           SLOC, DSUM);
  scan_combine<<<dim3(128), dim3(256), 0, stream>>>(SLOC, DSUM, A_log, HINIT);
  scan_part3<<<dim3(BB * NCH * 2), dim3(256), 0, stream>>>(DELTA, U, XDBC, XZ, A_log,
                                                           Dp, HINIT, Yhi, Ylo);

  // 9) out = Y @ out_proj_W.T   (grid 8x64 = 512)
  gemm_mfma<0><<<dim3(8 * 64), dim3(256), 0, stream>>>(
      Yhi, Ylo, Whi + (size_t)1536 * 512, Wlo + (size_t)1536 * 512, out, D_MODEL,
      D_INNER, 8, nullptr);
}

// Round 8
// 218.260 us; speedup vs baseline: 1.4378x; 1.0868x over previous
//
#include <hip/hip_runtime.h>
#include <hip/hip_bf16.h>
#include <math.h>

// Problem constants
#define D_MODEL 512
#define D_STATE 16
#define DT_RANK 32
#define D_INNER 512
#define BB 4
#define LL 2048
#define MROWS (BB * LL)   // 8192
#define LN_EPS 1e-5f
#define CHUNK 32
#define NCH (LL / CHUNK)  // 64
#define LOG2E 1.44269504f
#define LN2 0.69314718f

typedef __bf16 bf16x8 __attribute__((ext_vector_type(8)));
typedef float f32x4 __attribute__((ext_vector_type(4)));

// ---- bf16 split helpers (RNE) ----
__device__ __forceinline__ ushort f2bf(float x) {
  uint u = __float_as_uint(x);
  u = (u + 0x7fffu + ((u >> 16) & 1u)) >> 16;
  return (ushort)u;
}
__device__ __forceinline__ float bf2f(ushort h) {
  return __uint_as_float(((uint)h) << 16);
}
__device__ __forceinline__ void split2(float x, ushort& hi, ushort& lo) {
  hi = f2bf(x);
  lo = f2bf(x - bf2f(hi));
}

__device__ __forceinline__ void gload_lds16(const void* g, void* l) {
  __builtin_amdgcn_global_load_lds(
      (const __attribute__((address_space(1))) uint32_t*)g,
      (__attribute__((address_space(3))) uint32_t*)l, 16, 0, 0);
}

// ================= split-bf16 MFMA GEMM (r5/r7 structure, best measured) ======
// Tile 128x64, BK=32, double-buffered LDS + issue-early prefetch, LDS XOR
// swizzle, XCD-chunked block swizzle. A,B bf16 hi/lo pairs row-major [rows][K].
// EPI 0: C=acc.  EPI 1: relu(acc + e0[(row>>11)*512+col]).
// EPI 2: softplus(acc + e0[col]) via native exp2/log2.
template <int EPI>
__global__ __launch_bounds__(256) void gemm_mfma(const ushort* __restrict__ Ahi,
                                                 const ushort* __restrict__ Alo,
                                                 const ushort* __restrict__ Bhi,
                                                 const ushort* __restrict__ Blo,
                                                 float* __restrict__ C, int ldc, int K,
                                                 int nx, const float* __restrict__ e0) {
  __shared__ ushort sA[2][2][128][32];  // [buf][hi/lo][row][col]  32 KiB
  __shared__ ushort sB[2][2][64][32];   // 16 KiB

  const int tid = threadIdx.x;
  const int lane = tid & 63;
  const int wid = tid >> 6;  // 0..3

  // XCD-chunked bijective swizzle (nwg % 8 == 0 for all our grids)
  const int nwg = gridDim.x;
  const int q = nwg >> 3;
  const int t = (blockIdx.x & 7) * q + (blockIdx.x >> 3);
  const int bx = t % nx;
  const int by = t / nx;
  const int m0 = by * 128;
  const int n0 = bx * 64;

  // ---- staging addressing (pre-swizzled global source, linear LDS dest) ----
  const int srow = tid >> 2;                                  // 0..63
  const int koff = (((tid & 3) ^ ((tid >> 3) & 3)) << 3);     // swizzled k slot
  const ushort* Ah_p = Ahi + (size_t)(m0 + srow) * K + koff;
  const ushort* Al_p = Alo + (size_t)(m0 + srow) * K + koff;
  const ushort* Bh_p = Bhi + (size_t)(n0 + srow) * K + koff;
  const ushort* Bl_p = Blo + (size_t)(n0 + srow) * K + koff;
  const size_t rstep = (size_t)64 * K;
  const int wb = wid * 16;  // wave-uniform LDS row base

  // ---- compute addressing ----
  const int wr = wid >> 1, wc = wid & 1;     // wave 2x2 -> 64x32 sub-tile
  const int fr = lane & 15;
  const int rcs = (((lane >> 4) ^ ((fr >> 1) & 3)) << 3);  // swizzled read slot

  f32x4 acc[4][2] = {};

  auto STAGE = [&](int bq, int kk) {
    gload_lds16(Ah_p + kk,         &sA[bq][0][wb][0]);
    gload_lds16(Ah_p + kk + rstep, &sA[bq][0][64 + wb][0]);
    gload_lds16(Al_p + kk,         &sA[bq][1][wb][0]);
    gload_lds16(Al_p + kk + rstep, &sA[bq][1][64 + wb][0]);
    gload_lds16(Bh_p + kk,         &sB[bq][0][wb][0]);
    gload_lds16(Bl_p + kk,         &sB[bq][1][wb][0]);
  };

  int cur = 0;
  STAGE(0, 0);
  __syncthreads();

  for (int k0 = 0; k0 < K; k0 += 32) {
    if (k0 + 32 < K) STAGE(cur ^ 1, k0 + 32);  // prefetch in flight under MFMA
    bf16x8 ah[4], al[4], bh[2], bl[2];
#pragma unroll
    for (int m = 0; m < 4; ++m) {
      const int ar = wr * 64 + m * 16 + fr;
      ah[m] = *(const bf16x8*)&sA[cur][0][ar][rcs];
      al[m] = *(const bf16x8*)&sA[cur][1][ar][rcs];
    }
#pragma unroll
    for (int n = 0; n < 2; ++n) {
      const int br = wc * 32 + n * 16 + fr;
      bh[n] = *(const bf16x8*)&sB[cur][0][br][rcs];
      bl[n] = *(const bf16x8*)&sB[cur][1][br][rcs];
    }
#pragma unroll
    for (int m = 0; m < 4; ++m)
#pragma unroll
      for (int n = 0; n < 2; ++n) {
        acc[m][n] = __builtin_amdgcn_mfma_f32_16x16x32_bf16(ah[m], bh[n],
                                                            acc[m][n], 0, 0, 0);
        acc[m][n] = __builtin_amdgcn_mfma_f32_16x16x32_bf16(ah[m], bl[n],
                                                            acc[m][n], 0, 0, 0);
        acc[m][n] = __builtin_amdgcn_mfma_f32_16x16x32_bf16(al[m], bh[n],
                                                            acc[m][n], 0, 0, 0);
      }
    __syncthreads();
    cur ^= 1;
  }

  // epilogue: C/D layout col = lane&15, row = (lane>>4)*4 + r
  const int rbase = (lane >> 4) * 4;
#pragma unroll
  for (int m = 0; m < 4; ++m) {
    const int row0 = m0 + wr * 64 + m * 16 + rbase;
#pragma unroll
    for (int n = 0; n < 2; ++n) {
      const int col = n0 + wc * 32 + n * 16 + fr;
#pragma unroll
      for (int r = 0; r < 4; ++r) {
        float v = acc[m][n][r];
        const int row = row0 + r;
        if (EPI == 1) {
          v += e0[(row >> 11) * D_MODEL + col];
          v = fmaxf(v, 0.f);
        } else if (EPI == 2) {
          const float x = v + e0[col];
          const float e = __builtin_amdgcn_exp2f(-fabsf(x) * LOG2E);
          v = fmaxf(x, 0.f) + __log2f(1.f + e) * LN2;
        }
        C[(size_t)row * ldc + col] = v;
      }
    }
  }
}

// ================= BC GEMM: BC(M,32) = A(M,512) @ Wbc(32,512)^T ===============
// M-tile 64, grid M/64 = 128 blocks, dbuf prefetch, same swizzle discipline.
__global__ __launch_bounds__(256) void bc_gemm(const ushort* __restrict__ Ahi,
                                               const ushort* __restrict__ Alo,
                                               const ushort* __restrict__ Bhi,
                                               const ushort* __restrict__ Blo,
                                               float* __restrict__ BC) {
  __shared__ ushort sA[2][2][64][32];  // 16 KiB
  __shared__ ushort sB[2][2][32][32];  // 8 KiB
  const int K = 512;
  const int tid = threadIdx.x;
  const int lane = tid & 63;
  const int wid = tid >> 6;
  const int m0 = blockIdx.x * 64;

  const int srow = lane >> 2;  // 0..15
  const int koff = (((lane & 3) ^ ((lane >> 3) & 3)) << 3);
  // A: wave wid stages rows wid*16 + srow (hi and lo)
  const ushort* Ah_p = Ahi + (size_t)(m0 + wid * 16 + srow) * K + koff;
  const ushort* Al_p = Alo + (size_t)(m0 + wid * 16 + srow) * K + koff;
  // B: waves 0,1 -> hi rows 0..15 / 16..31 ; waves 2,3 -> lo rows 0..15 / 16..31
  const ushort* B_p = ((wid < 2) ? Bhi : Blo) + (size_t)((wid & 1) * 16 + srow) * K + koff;

  const int wr = wid >> 1, wc = wid & 1;  // rows wr*32+{0,16}, cols wc*16
  const int fr = lane & 15;
  const int rcs = (((lane >> 4) ^ ((fr >> 1) & 3)) << 3);

  f32x4 acc[2] = {};

  auto STAGE = [&](int bq, int kk) {
    gload_lds16(Ah_p + kk, &sA[bq][0][wid * 16][0]);
    gload_lds16(Al_p + kk, &sA[bq][1][wid * 16][0]);
    gload_lds16(B_p + kk, &sB[bq][wid >> 1][(wid & 1) * 16][0]);
  };

  int cur = 0;
  STAGE(0, 0);
  __syncthreads();

  for (int k0 = 0; k0 < K; k0 += 32) {
    if (k0 + 32 < K) STAGE(cur ^ 1, k0 + 32);
    bf16x8 ah[2], al[2], bh, bl;
#pragma unroll
    for (int m = 0; m < 2; ++m) {
      const int ar = wr * 32 + m * 16 + fr;
      ah[m] = *(const bf16x8*)&sA[cur][0][ar][rcs];
      al[m] = *(const bf16x8*)&sA[cur][1][ar][rcs];
    }
    const int br = wc * 16 + fr;
    bh = *(const bf16x8*)&sB[cur][0][br][rcs];
    bl = *(const bf16x8*)&sB[cur][1][br][rcs];
#pragma unroll
    for (int m = 0; m < 2; ++m) {
      acc[m] = __builtin_amdgcn_mfma_f32_16x16x32_bf16(ah[m], bh, acc[m], 0, 0, 0);
      acc[m] = __builtin_amdgcn_mfma_f32_16x16x32_bf16(ah[m], bl, acc[m], 0, 0, 0);
      acc[m] = __builtin_amdgcn_mfma_f32_16x16x32_bf16(al[m], bh, acc[m], 0, 0, 0);
    }
    __syncthreads();
    cur ^= 1;
  }

  const int rbase = (lane >> 4) * 4;
  const int col = wc * 16 + fr;
#pragma unroll
  for (int m = 0; m < 2; ++m) {
    const int row0 = m0 + wr * 32 + m * 16 + rbase;
#pragma unroll
    for (int r = 0; r < 4; ++r)
      BC[(size_t)(row0 + r) * 32 + col] = acc[m][r];
  }
}

// ---------------- splitters ---------------------------------------------------
__global__ __launch_bounds__(256) void split_x(const float* __restrict__ x,
                                               ushort* __restrict__ hi,
                                               ushort* __restrict__ lo) {
  const int i = (blockIdx.x * 256 + threadIdx.x) * 4;
  float4 v = *(const float4*)(x + i);
  ushort h0, l0, h1, l1, h2, l2, h3, l3;
  split2(v.x, h0, l0); split2(v.y, h1, l1); split2(v.z, h2, l2); split2(v.w, h3, l3);
  ushort4 hv = {h0, h1, h2, h3}, lv = {l0, l1, l2, l3};
  *(ushort4*)(hi + i) = hv;
  *(ushort4*)(lo + i) = lv;
}

// weight splitter rows 0..2047: [gW1a | in_proj_W | out_proj_W]
__global__ __launch_bounds__(128) void split_w(const float* __restrict__ gW1,
                                               const float* __restrict__ ipW,
                                               const float* __restrict__ opW,
                                               ushort* __restrict__ Whi,
                                               ushort* __restrict__ Wlo) {
  const int r = blockIdx.x;
  const int t = threadIdx.x;
  const float* src;
  if (r < 512) src = gW1 + (size_t)r * 1024;
  else if (r < 1536) src = ipW + (size_t)(r - 512) * 512;
  else src = opW + (size_t)(r - 1536) * 512;
  const int i = t * 4;
  float4 v = *(const float4*)(src + i);
  ushort h0, l0, h1, l1, h2, l2, h3, l3;
  split2(v.x, h0, l0); split2(v.y, h1, l1); split2(v.z, h2, l2); split2(v.w, h3, l3);
  ushort4 hv = {h0, h1, h2, h3}, lv = {l0, l1, l2, l3};
  *(ushort4*)(Whi + (size_t)r * 512 + i) = hv;
  *(ushort4*)(Wlo + (size_t)r * 512 + i) = lv;
}

// fused x-projection weights, rows 2048..2591:
//  j<512:       row 2048+j = W_comb[j] = dt_proj_W[j,:] @ x_proj_W[:32,:]
//  512<=j<544:  row 2048+j (=2560..2591) = x_proj_W rows 32..63 (B,C rows)
__global__ __launch_bounds__(128) void build_xw(const float* __restrict__ xW,
                                                const float* __restrict__ dtW,
                                                ushort* __restrict__ Whi,
                                                ushort* __restrict__ Wlo) {
  const int j = blockIdx.x;
  const int t = threadIdx.x;
  float v[4] = {0.f, 0.f, 0.f, 0.f};
  if (j < 512) {
    __shared__ float sdt[32];
    if (t < 32) sdt[t] = dtW[j * 32 + t];
    __syncthreads();
    const int k = t * 4;
#pragma unroll 8
    for (int r = 0; r < 32; ++r) {
      const float w = sdt[r];
      const float4 xv = *(const float4*)(xW + r * 512 + k);
      v[0] = fmaf(w, xv.x, v[0]);
      v[1] = fmaf(w, xv.y, v[1]);
      v[2] = fmaf(w, xv.z, v[2]);
      v[3] = fmaf(w, xv.w, v[3]);
    }
  } else {
    const float4 xv = *(const float4*)(xW + (size_t)(32 + j - 512) * 512 + t * 4);
    v[0] = xv.x; v[1] = xv.y; v[2] = xv.z; v[3] = xv.w;
  }
  ushort h[4], l[4];
#pragma unroll
  for (int c = 0; c < 4; ++c) split2(v[c], h[c], l[c]);
  const size_t off = (size_t)(2048 + j) * 512 + t * 4;
  ushort4 hv = {h[0], h[1], h[2], h[3]}, lv = {l[0], l[1], l[2], l[3]};
  *(ushort4*)(Whi + off) = hv;
  *(ushort4*)(Wlo + off) = lv;
}

// ---------------- per-batch constant -----------------------------------------
__global__ __launch_bounds__(512) void c1_kernel(const float* __restrict__ xstats,
                                                 const float* __restrict__ gW1,
                                                 const float* __restrict__ gb1,
                                                 float* __restrict__ c1) {
  const int b = blockIdx.x;
  const int j = threadIdx.x;
  float acc = gb1[j];
  const float* xs = xstats + b * D_MODEL;
  const float* w = gW1 + (size_t)j * (2 * D_MODEL) + D_MODEL;
  for (int k = 0; k < D_MODEL; k += 4) {
    acc = fmaf(xs[k], w[k], acc);
    acc = fmaf(xs[k + 1], w[k + 1], acc);
    acc = fmaf(xs[k + 2], w[k + 2], acc);
    acc = fmaf(xs[k + 3], w[k + 3], acc);
  }
  c1[b * D_MODEL + j] = acc;
}

// ---------------- block reduce ------------------------------------------------
__device__ __forceinline__ float block_sum(float v, float* sm) {
#pragma unroll
  for (int m = 32; m; m >>= 1) v += __shfl_xor(v, m);
  const int lane = threadIdx.x & 63, w = threadIdx.x >> 6;
  __syncthreads();
  if (!lane) sm[w] = v;
  __syncthreads();
  return sm[0] + sm[1] + sm[2] + sm[3];
}

// ---------------- gate + layernorm (writes bf16 hi/lo) -------------------------
__global__ __launch_bounds__(256) void gate_ln_kernel(const float* __restrict__ H,
                                                      const float* __restrict__ xsig,
                                                      const float* __restrict__ xstats,
                                                      const float* __restrict__ gW2,
                                                      const float* __restrict__ gb2,
                                                      const float* __restrict__ ln_g,
                                                      const float* __restrict__ ln_b,
                                                      ushort* __restrict__ XNhi,
                                                      ushort* __restrict__ XNlo) {
  __shared__ float red[4];
  const int row = blockIdx.x;
  const int b = row >> 11;
  const int tid = threadIdx.x;
  const size_t rb = (size_t)row * D_MODEL;

  float dotv = 0.f;
  for (int j = tid; j < D_MODEL; j += 256) dotv = fmaf(H[rb + j], gW2[j], dotv);
  const float s = block_sum(dotv, red);
  const float gate = 1.f / (1.f + expf(-(s + gb2[0])));

  float xr[2];
#pragma unroll
  for (int ii = 0; ii < 2; ++ii) {
    const int j = tid + ii * 256;
    xr[ii] = xsig[rb + j] + gate * xstats[b * D_MODEL + j];
  }
  float sv = xr[0] + xr[1];
  const float mu = block_sum(sv, red) * (1.f / D_MODEL);
  float s2 = (xr[0] - mu) * (xr[0] - mu) + (xr[1] - mu) * (xr[1] - mu);
  const float var = block_sum(s2, red) * (1.f / D_MODEL);
  const float inv = rsqrtf(var + LN_EPS);
#pragma unroll
  for (int ii = 0; ii < 2; ++ii) {
    const int j = tid + ii * 256;
    const float v = (xr[ii] - mu) * inv * ln_g[j] + ln_b[j];
    ushort h, l;
    split2(v, h, l);
    XNhi[rb + j] = h;
    XNlo[rb + j] = l;
  }
}

// ---------------- causal conv(2) + SiLU (emits bf16 hi/lo only) ----------------
__global__ __launch_bounds__(256) void conv_silu_kernel(const float* __restrict__ XZ,
                                                        const float* __restrict__ conv_w,
                                                        const float* __restrict__ conv_b,
                                                        ushort* __restrict__ Uhi,
                                                        ushort* __restrict__ Ulo) {
  const int row = blockIdx.x;
  const bool first = (row & (LL - 1)) == 0;
  const int tid = threadIdx.x;
#pragma unroll
  for (int ii = 0; ii < 2; ++ii) {
    const int j = tid + ii * 256;
    const float up = first ? 0.f : XZ[(size_t)(row - 1) * (2 * D_INNER) + j];
    const float uc = XZ[(size_t)row * (2 * D_INNER) + j];
    float v = conv_b[j] + conv_w[j * 2 + 0] * up + conv_w[j * 2 + 1] * uc;
    v = v / (1.f + expf(-v));
    ushort h, l;
    split2(v, h, l);
    Uhi[(size_t)row * D_INNER + j] = h;
    Ulo[(size_t)row * D_INNER + j] = l;
  }
}

// ---------------- chunked selective scan (lane = channel, states in regs) ------
__global__ __launch_bounds__(256) void scan_part1(const float* __restrict__ DELTA,
                                                  const ushort* __restrict__ Uhi,
                                                  const ushort* __restrict__ Ulo,
                                                  const float* __restrict__ BC,
                                                  const float* __restrict__ A_log,
                                                  float* __restrict__ SLOC,
                                                  float* __restrict__ DSUM) {
  __shared__ __align__(16) float sBC[CHUNK][32];
  const int tid = threadIdx.x;
  const int bid = blockIdx.x;
  const int d = ((bid & 1) << 8) + tid;
  const int c = (bid >> 1) & (NCH - 1);
  const int b = bid >> 7;
  const size_t base = (size_t)b * LL + (size_t)c * CHUNK;

  {
    const int row = tid >> 3, col = (tid & 7) << 2;
    *(float4*)&sBC[row][col] = *(const float4*)(BC + (base + row) * 32 + col);
  }
  float A2[16];
#pragma unroll
  for (int n = 0; n < 16; ++n) A2[n] = -expf(A_log[d * 16 + n]) * LOG2E;
  __syncthreads();

  float S[16];
#pragma unroll
  for (int n = 0; n < 16; ++n) S[n] = 0.f;
  float dsum = 0.f;

#pragma unroll 2
  for (int t = 0; t < CHUNK; ++t) {
    const size_t r = base + t;
    const float delta = DELTA[r * D_INNER + d];
    const float u = bf2f(Uhi[r * D_INNER + d]) + bf2f(Ulo[r * D_INNER + d]);
    dsum += delta;
    const float du = delta * u;
    float Bv[16];
#pragma unroll
    for (int i = 0; i < 4; ++i)
      *(float4*)&Bv[i * 4] = *(const float4*)&sBC[t][i * 4];
#pragma unroll
    for (int n = 0; n < 16; ++n) {
      const float dA = __builtin_amdgcn_exp2f(delta * A2[n]);
      S[n] = fmaf(dA, S[n], du * Bv[n]);
    }
  }
  const size_t ci = ((size_t)b * NCH + c) * D_INNER + d;
#pragma unroll
  for (int i = 0; i < 4; ++i)
    *(float4*)(SLOC + ci * 16 + i * 4) = *(const float4*)&S[i * 4];
  DSUM[ci] = dsum;
}

__global__ __launch_bounds__(256) void scan_combine(const float* __restrict__ SLOC,
                                                    const float* __restrict__ DSUM,
                                                    const float* __restrict__ A_log,
                                                    float* __restrict__ HINIT) {
  const int idx = blockIdx.x * 256 + threadIdx.x;  // 0..32767
  const int b = idx >> 13;
  const int d = (idx >> 4) & (D_INNER - 1);
  const int n = idx & 15;
  const float A2 = -expf(A_log[d * D_STATE + n]) * LOG2E;
  float h = 0.f;
#pragma unroll 4
  for (int c = 0; c < NCH; ++c) {
    const size_t ci = ((size_t)b * NCH + c) * D_INNER + d;
    HINIT[ci * 16 + n] = h;
    const float a = __builtin_amdgcn_exp2f(A2 * DSUM[ci]);
    h = fmaf(a, h, SLOC[ci * 16 + n]);
  }
}

__global__ __launch_bounds__(256) void scan_part3(const float* __restrict__ DELTA,
                                                  const ushort* __restrict__ Uhi,
                                                  const ushort* __restrict__ Ulo,
                                                  const float* __restrict__ BC,
                                                  const float* __restrict__ XZ,
                                                  const float* __restrict__ A_log,
                                                  const float* __restrict__ Dp,
                                                  const float* __restrict__ HINIT,
                                                  ushort* __restrict__ Yhi,
                                                  ushort* __restrict__ Ylo) {
  __shared__ __align__(16) float sBC[CHUNK][32];
  const int tid = threadIdx.x;
  const int bid = blockIdx.x;
  const int d = ((bid & 1) << 8) + tid;
  const int c = (bid >> 1) & (NCH - 1);
  const int b = bid >> 7;
  const size_t base = (size_t)b * LL + (size_t)c * CHUNK;

  {
    const int row = tid >> 3, col = (tid & 7) << 2;
    *(float4*)&sBC[row][col] = *(const float4*)(BC + (base + row) * 32 + col);
  }
  float A2[16];
#pragma unroll
  for (int n = 0; n < 16; ++n) A2[n] = -expf(A_log[d * 16 + n]) * LOG2E;
  const float Dpd = Dp[d];

  const size_t ci = ((size_t)b * NCH + c) * D_INNER + d;
  float h[16];
#pragma unroll
  for (int i = 0; i < 4; ++i)
    *(float4*)&h[i * 4] = *(const float4*)(HINIT + ci * 16 + i * 4);
  __syncthreads();

#pragma unroll 2
  for (int t = 0; t < CHUNK; ++t) {
    const size_t r = base + t;
    const float delta = DELTA[r * D_INNER + d];
    const float u = bf2f(Uhi[r * D_INNER + d]) + bf2f(Ulo[r * D_INNER + d]);
    const float z = XZ[r * (2 * D_INNER) + D_INNER + d];
    const float du = delta * u;
    float BCv[32];
#pragma unroll
    for (int i = 0; i < 8; ++i)
      *(float4*)&BCv[i * 4] = *(const float4*)&sBC[t][i * 4];
    float y = 0.f;
#pragma unroll
    for (int n = 0; n < 16; ++n) {
      const float dA = __builtin_amdgcn_exp2f(delta * A2[n]);
      h[n] = fmaf(dA, h[n], du * BCv[n]);
      y = fmaf(h[n], BCv[16 + n], y);
    }
    const float sz = z / (1.f + __builtin_amdgcn_exp2f(-z * LOG2E));
    const float o = (y + Dpd * u) * sz;
    ushort hh, ll;
    split2(o, hh, ll);
    Yhi[r * D_INNER + d] = hh;
    Ylo[r * D_INNER + d] = ll;
  }
}

// =============================================================================
extern "C" void kernel_launch(void* const* d_in, const int* in_sizes, int n_in,
                              void* d_out, int out_size, void* d_ws, size_t ws_size,
                              hipStream_t stream) {
  const float* x_signal = (const float*)d_in[0];
  const float* x_stats  = (const float*)d_in[1];
  const float* gW1      = (const float*)d_in[2];
  const float* gb1      = (const float*)d_in[3];
  const float* gW2      = (const float*)d_in[4];
  const float* gb2      = (const float*)d_in[5];
  const float* ln_g     = (const float*)d_in[6];
  const float* ln_b     = (const float*)d_in[7];
  const float* in_proj_W = (const float*)d_in[8];
  const float* conv_w   = (const float*)d_in[9];
  const float* conv_b   = (const float*)d_in[10];
  const float* x_proj_W = (const float*)d_in[11];
  const float* dt_proj_W = (const float*)d_in[12];
  const float* dt_proj_b = (const float*)d_in[13];
  const float* A_log    = (const float*)d_in[14];
  const float* Dp       = (const float*)d_in[15];
  const float* out_proj_W = (const float*)d_in[16];
  float* out = (float*)d_out;

  float* ws = (float*)d_ws;
  const size_t NE = (size_t)MROWS * D_MODEL;  // 4,194,304
  float* H    = ws;                     // gate GEMM out; reused as Yhi/Ylo
  float* XNf  = H + NE;                 // XN hi/lo bf16; later DELTA f32
  float* XZ   = XNf + NE;               // 8192x1024 f32; first XShi/XSlo
  float* UHL  = XZ + 2 * NE;            // Uhi/Ulo bf16
  float* BC   = UHL + NE;               // 8192x32 f32
  float* C1   = BC + (size_t)MROWS * 32;
  float* SLOC = C1 + BB * D_MODEL;
  float* DSUM = SLOC + (size_t)BB * NCH * D_INNER * D_STATE;
  float* HINIT = DSUM + (size_t)BB * NCH * D_INNER;
  float* WSP  = HINIT + (size_t)BB * NCH * D_INNER * D_STATE;

  ushort* XNhi = (ushort*)XNf;
  ushort* XNlo = XNhi + NE;
  ushort* XShi = (ushort*)XZ;
  ushort* XSlo = XShi + NE;
  ushort* Yhi  = (ushort*)H;
  ushort* Ylo  = Yhi + NE;
  ushort* Uhi  = (ushort*)UHL;
  ushort* Ulo  = Uhi + NE;
  ushort* Whi  = (ushort*)WSP;          // 2592 rows x 512
  ushort* Wlo  = Whi + (size_t)2592 * 512;
  float* DELTA = XNf;

  // 0) splits + fused x-projection weights
  split_x<<<dim3(NE / 1024), dim3(256), 0, stream>>>(x_signal, XShi, XSlo);
  split_w<<<dim3(2048), dim3(128), 0, stream>>>(gW1, in_proj_W, out_proj_W, Whi, Wlo);
  build_xw<<<dim3(544), dim3(128), 0, stream>>>(x_proj_W, dt_proj_W, Whi, Wlo);

  // 1) per-batch xs @ W1b.T + gb1
  c1_kernel<<<dim3(BB), dim3(512), 0, stream>>>(x_stats, gW1, gb1, C1);

  // 2) H = relu(x_signal @ W1a.T + c1)   (grid 8x64 = 512)
  gemm_mfma<1><<<dim3(8 * 64), dim3(256), 0, stream>>>(
      XShi, XSlo, Whi, Wlo, H, D_MODEL, D_MODEL, 8, C1);

  // 3) gate + layernorm -> XNhi/XNlo
  gate_ln_kernel<<<dim3(MROWS), dim3(256), 0, stream>>>(H, x_signal, x_stats, gW2, gb2,
                                                        ln_g, ln_b, XNhi, XNlo);

  // 4) XZ = XN @ in_proj_W.T   (grid 16x64 = 1024)
  gemm_mfma<0><<<dim3(16 * 64), dim3(256), 0, stream>>>(
      XNhi, XNlo, Whi + (size_t)512 * 512, Wlo + (size_t)512 * 512, XZ, 2 * D_INNER,
      D_MODEL, 16, nullptr);

  // 5) conv + silu -> Uhi/Ulo
  conv_silu_kernel<<<dim3(MROWS), dim3(256), 0, stream>>>(XZ, conv_w, conv_b, Uhi, Ulo);

  // 6a) DELTA = softplus(U @ Wcomb.T + dtb)  (grid 8x64 = 512, gate-GEMM shape)
  gemm_mfma<2><<<dim3(8 * 64), dim3(256), 0, stream>>>(
      Uhi, Ulo, Whi + (size_t)2048 * 512, Wlo + (size_t)2048 * 512, DELTA, 512,
      D_MODEL, 8, dt_proj_b);

  // 6b) BC = U @ xWbc.T  (N=32, grid 128)
  bc_gemm<<<dim3(MROWS / 64), dim3(256), 0, stream>>>(
      Uhi, Ulo, Whi + (size_t)2560 * 512, Wlo + (size_t)2560 * 512, BC);

  // 7) chunked selective scan -> Yhi/Ylo
  scan_part1<<<dim3(BB * NCH * 2), dim3(256), 0, stream>>>(DELTA, Uhi, Ulo, BC, A_log,
                                                           SLOC, DSUM);
  scan_combine<<<dim3(128), dim3(256), 0, stream>>>(SLOC, DSUM, A_log, HINIT);
  scan_part3<<<dim3(BB * NCH * 2), dim3(256), 0, stream>>>(DELTA, Uhi, Ulo, BC, XZ,
                                                           A_log, Dp, HINIT, Yhi, Ylo);

  // 8) out = Y @ out_proj_W.T   (grid 8x64 = 512)
  gemm_mfma<0><<<dim3(8 * 64), dim3(256), 0, stream>>>(
      Yhi, Ylo, Whi + (size_t)1536 * 512, Wlo + (size_t)1536 * 512, out, D_MODEL,
      D_INNER, 8, nullptr);
}